// Round 4
// baseline (695.539 us; speedup 1.0000x reference)
//
#include <hip/hip_runtime.h>
#include <cstdint>

#define EPSV 1e-5f
typedef unsigned short u16;
typedef __attribute__((ext_vector_type(8))) short bh8;   // 8 bf16 (4 VGPRs)
typedef __attribute__((ext_vector_type(4))) float f4;

__device__ __forceinline__ float bf2f(u16 h) { return __uint_as_float((unsigned)h << 16); }
__device__ __forceinline__ u16 f2bf(float x) {
    unsigned u = __float_as_uint(x);
    u += 0x7fffu + ((u >> 16) & 1u);          // RNE
    return (u16)(u >> 16);
}

// async global->LDS, 16B per lane; LDS dest = wave-uniform base + lane*16
__device__ __forceinline__ void gl16(const void* g, const void* s) {
    __builtin_amdgcn_global_load_lds(
        reinterpret_cast<const __attribute__((address_space(1))) void*>((uintptr_t)g),
        reinterpret_cast<__attribute__((address_space(3))) void*>((unsigned)(uintptr_t)s),
        16, 0, 0);
}

// ---------------------------------------------------------------------------
// Stage one 128x32 hi/lo A-tile + 128x32 hi/lo B-tile into one LDS buffer.
// Buffer layout (bytes): Ah[0,8192) Al[8192,16384) Bh[16384,24576) Bl[24576,32768)
// Each plane is row-major [128][32] bf16. base includes w*1024.
// ---------------------------------------------------------------------------
__device__ __forceinline__ void stage_tiles(
    const u16* __restrict__ Ah, const u16* __restrict__ Al,
    const u16* __restrict__ Bh, const u16* __restrict__ Bl,
    size_t aoff, size_t boff, size_t ldA64, size_t ldB64,
    char* base, int s0)
{
    gl16(Ah + aoff + s0, base);
    gl16(Ah + aoff + ldA64 + s0, base + 4096);
    gl16(Al + aoff + s0, base + 8192);
    gl16(Al + aoff + ldA64 + s0, base + 12288);
    gl16(Bh + boff + s0, base + 16384);
    gl16(Bh + boff + ldB64 + s0, base + 20480);
    gl16(Bl + boff + s0, base + 24576);
    gl16(Bl + boff + ldB64 + s0, base + 28672);
}

// ---------------------------------------------------------------------------
// 2-phase double-buffered 128x128 NT hi/lo GEMM core (4 waves, 64 KB LDS).
// acc += (Ahi+Alo)*(Bhi+Blo)^T over K (3 MFMA passes: hh, hl, lh).
// Loads of tile t+1 are issued before compute of tile t; the single
// __syncthreads per K-step drains them after MFMA has covered the latency.
// ---------------------------------------------------------------------------
__device__ __forceinline__ void core2(
    const u16* __restrict__ Ah, const u16* __restrict__ Al,
    const u16* __restrict__ Bh, const u16* __restrict__ Bl,
    long ldA, long ldB, int K, int rowA0, int rowB0,
    u16* lds, f4 acc[4][4])
{
    const int tid = threadIdx.x, l = tid & 63, w = tid >> 6;
    const int r0 = tid >> 2;              // staging row 0..63
    const int c0e = (tid & 3) << 3;       // staging k-offset (elems)
    const int wr = w >> 1, wc = w & 1;
    const int lk = (l >> 4) << 3, lm = l & 15;
    const size_t aoff = (size_t)(rowA0 + r0) * ldA + c0e;
    const size_t boff = (size_t)(rowB0 + r0) * ldB + c0e;
    const size_t ldA64 = (size_t)64 * ldA, ldB64 = (size_t)64 * ldB;
    char* const base0 = (char*)lds + w * 1024;
    char* const base1 = (char*)lds + 32768 + w * 1024;
    const int nt = K >> 5;

    stage_tiles(Ah, Al, Bh, Bl, aoff, boff, ldA64, ldB64, base0, 0);
    __syncthreads();
    int p = 0;
    for (int t = 0; t < nt; ++t) {
        if (t + 1 < nt)
            stage_tiles(Ah, Al, Bh, Bl, aoff, boff, ldA64, ldB64,
                        p ? base0 : base1, (t + 1) << 5);
        const u16* buf = lds + p * 16384;
        bh8 a_h[4], a_l[4], b_h[4], b_l[4];
#pragma unroll
        for (int i = 0; i < 4; ++i) {
            const int ar = (wr * 64 + i * 16 + lm) * 32 + lk;
            const int br = (wc * 64 + i * 16 + lm) * 32 + lk;
            a_h[i] = *(const bh8*)&buf[ar];
            a_l[i] = *(const bh8*)&buf[4096 + ar];
            b_h[i] = *(const bh8*)&buf[8192 + br];
            b_l[i] = *(const bh8*)&buf[12288 + br];
        }
#pragma unroll
        for (int i = 0; i < 4; ++i)
#pragma unroll
            for (int j = 0; j < 4; ++j)
                acc[i][j] = __builtin_amdgcn_mfma_f32_16x16x32_bf16(a_h[i], b_h[j], acc[i][j], 0, 0, 0);
#pragma unroll
        for (int i = 0; i < 4; ++i)
#pragma unroll
            for (int j = 0; j < 4; ++j)
                acc[i][j] = __builtin_amdgcn_mfma_f32_16x16x32_bf16(a_h[i], b_l[j], acc[i][j], 0, 0, 0);
#pragma unroll
        for (int i = 0; i < 4; ++i)
#pragma unroll
            for (int j = 0; j < 4; ++j)
                acc[i][j] = __builtin_amdgcn_mfma_f32_16x16x32_bf16(a_l[i], b_h[j], acc[i][j], 0, 0, 0);
        __syncthreads();
        p ^= 1;
    }
}

// ---------------------------------------------------------------------------
// Stage-1: Yt[c][o] = relu(bn(sum_s X[c,s]*W[o,s])) as hi/lo planes [B*512][640]
// 1920 blocks = 8 XCD chunks * 240; within chunk: o-tile/weight fastest.
// ---------------------------------------------------------------------------
__global__ __launch_bounds__(256) void gemm_s1_v3(
    const u16* __restrict__ Xh, const u16* __restrict__ Xl,
    const u16* __restrict__ W0h, const u16* __restrict__ W0l,
    const u16* __restrict__ W1h, const u16* __restrict__ W1l,
    const u16* __restrict__ W2h, const u16* __restrict__ W2l,
    const float* __restrict__ bn0, const float* __restrict__ bn1,
    const float* __restrict__ bn2,
    u16* __restrict__ Y0h, u16* __restrict__ Y0l,
    u16* __restrict__ Y1h, u16* __restrict__ Y1l,
    u16* __restrict__ Y2h, u16* __restrict__ Y2l)
{
    const int h = blockIdx.x;
    const int orig = (h & 7) * 240 + (h >> 3);
    const int ow = orig % 15;
    const int rest = orig / 15;
    const int ct = rest & 3, bz = rest >> 2;
    const int wi = ow / 5, otw = ow % 5;

    const u16* Bh = wi == 0 ? W0h : wi == 1 ? W1h : W2h;
    const u16* Bl = wi == 0 ? W0l : wi == 1 ? W1l : W2l;
    const float* bnp = wi == 0 ? bn0 : wi == 1 ? bn1 : bn2;
    u16* Yh = wi == 0 ? Y0h : wi == 1 ? Y1h : Y2h;
    u16* Yl = wi == 0 ? Y0l : wi == 1 ? Y1l : Y2l;

    __shared__ u16 lds[32768];
    f4 acc[4][4];
    const f4 z4 = {0.f, 0.f, 0.f, 0.f};
#pragma unroll
    for (int i = 0; i < 4; ++i)
#pragma unroll
        for (int j = 0; j < 4; ++j) acc[i][j] = z4;

    core2(Xh, Xl, Bh, Bl, 2304, 2304, 2304,
          bz * 512 + ct * 128, otw * 128, lds, acc);

    const int l = threadIdx.x & 63, w = threadIdx.x >> 6;
    const int wr = w >> 1, wc = w & 1;
    const int mb = ct * 128 + wr * 64;        // c within batch
    const int nbw = otw * 128 + wc * 64;      // o
    const int lm = l & 15;
#pragma unroll
    for (int j = 0; j < 4; ++j) {
        const int o = nbw + j * 16 + lm;
        const bool val = (o < 576);
        float sc = 0.f, sh = 0.f;
        if (val) {
            const float gg = bnp[o], be = bnp[576 + o], mm = bnp[1152 + o], vv = bnp[1728 + o];
            sc = gg * rsqrtf(vv + EPSV);
            sh = be - mm * sc;
        }
#pragma unroll
        for (int i = 0; i < 4; ++i) {
            const int c = mb + i * 16 + ((l >> 4) << 2);
#pragma unroll
            for (int r = 0; r < 4; ++r) {
                const float y = val ? fmaxf(acc[i][j][r] * sc + sh, 0.f) : 0.f;
                const u16 hh = f2bf(y);
                const u16 lo = f2bf(y - bf2f(hh));
                const size_t off = ((size_t)bz * 512 + c + r) * 640 + o;
                Yh[off] = hh; Yl[off] = lo;
            }
        }
    }
}

// ---------------------------------------------------------------------------
// U GEMMs: U1[i][o] = sum_j Wgg[i][j]   * phi_nt[o][j]   (phi_nt[o][j]=phi_t[j][o])
//          U2[i][o] = sum_j Wgg[i][512+j]* theta_nt[o][j]
// written as hi/lo planes [32][128][640]. 320 blocks = 8*40 swizzle.
// ---------------------------------------------------------------------------
__global__ __launch_bounds__(256) void gemm_u(
    const u16* __restrict__ Wggh, const u16* __restrict__ Wggl,
    const u16* __restrict__ tnth, const u16* __restrict__ tntl,
    const u16* __restrict__ pnth, const u16* __restrict__ pntl,
    u16* __restrict__ U1h, u16* __restrict__ U1l,
    u16* __restrict__ U2h, u16* __restrict__ U2l)
{
    const int h = blockIdx.x;
    const int orig = (h & 7) * 40 + (h >> 3);
    const int ot = orig % 5;
    const int rest = orig / 5;
    const int u = rest & 1, b = rest >> 1;

    const u16* Ah = Wggh + (u ? 512 : 0);
    const u16* Al = Wggl + (u ? 512 : 0);
    const u16* Bh = u ? tnth : pnth;
    const u16* Bl = u ? tntl : pntl;

    __shared__ u16 lds[32768];
    f4 acc[4][4];
    const f4 z4 = {0.f, 0.f, 0.f, 0.f};
#pragma unroll
    for (int i = 0; i < 4; ++i)
#pragma unroll
        for (int j = 0; j < 4; ++j) acc[i][j] = z4;

    core2(Ah, Al, Bh, Bl, 1024, 512, 512, 0, b * 640 + ot * 128, lds, acc);

    u16* Uh = u ? U2h : U1h;
    u16* Ul = u ? U2l : U1l;
    const int l = threadIdx.x & 63, w = threadIdx.x >> 6;
    const int wr = w >> 1, wc = w & 1;
#pragma unroll
    for (int i = 0; i < 4; ++i)
#pragma unroll
        for (int j = 0; j < 4; ++j)
#pragma unroll
            for (int r = 0; r < 4; ++r) {
                const int irow = wr * 64 + i * 16 + ((l >> 4) << 2) + r;
                const int ocol = ot * 128 + wc * 64 + j * 16 + (l & 15);
                const float v = acc[i][j][r];
                const u16 hh = f2bf(v);
                const u16 lo = f2bf(v - bf2f(hh));
                const size_t off = ((size_t)b * 128 + irow) * 640 + ocol;
                Uh[off] = hh; Ul[off] = lo;
            }
}

// ---------------------------------------------------------------------------
// GG[b][i][d] = relu(bn_gg(sum_o theta_t[d][o]*U1[i][o] + phi_t[d][o]*U2[i][o]))
// 128 blocks = 8*16 swizzle.
// ---------------------------------------------------------------------------
__global__ __launch_bounds__(256) void gemm_term(
    const u16* __restrict__ U1h, const u16* __restrict__ U1l,
    const u16* __restrict__ U2h, const u16* __restrict__ U2l,
    const u16* __restrict__ tth, const u16* __restrict__ ttl,
    const u16* __restrict__ pth, const u16* __restrict__ ptl,
    const float* __restrict__ bn, float* __restrict__ GG)
{
    const int h = blockIdx.x;
    const int orig = (h & 7) * 16 + (h >> 3);
    const int dt = orig & 3, b = orig >> 2;

    __shared__ u16 lds[32768];
    f4 acc[4][4];
    const f4 z4 = {0.f, 0.f, 0.f, 0.f};
#pragma unroll
    for (int i = 0; i < 4; ++i)
#pragma unroll
        for (int j = 0; j < 4; ++j) acc[i][j] = z4;

    core2(U1h, U1l, tth, ttl, 640, 640, 640,
          b * 128, b * 512 + dt * 128, lds, acc);
    core2(U2h, U2l, pth, ptl, 640, 640, 640,
          b * 128, b * 512 + dt * 128, lds, acc);

    const int l = threadIdx.x & 63, w = threadIdx.x >> 6;
    const int wr = w >> 1, wc = w & 1;
#pragma unroll
    for (int i = 0; i < 4; ++i)
#pragma unroll
        for (int r = 0; r < 4; ++r) {
            const int irow = wr * 64 + i * 16 + ((l >> 4) << 2) + r;
            const float g = bn[irow], be = bn[128 + irow], m = bn[256 + irow], v = bn[384 + irow];
            const float sc = g * rsqrtf(v + EPSV);
            const float sh = be - m * sc;
#pragma unroll
            for (int j = 0; j < 4; ++j) {
                const int dcol = dt * 128 + wc * 64 + j * 16 + (l & 15);
                GG[((size_t)b * 128 + irow) * 512 + dcol] =
                    fmaxf(acc[i][j][r] * sc + sh, 0.f);
            }
        }
}

// ---------------------------------------------------------------------------
// transpose: src [b*512+c][640] -> dst [b*640+o][512], 4 planes via z
// ---------------------------------------------------------------------------
__global__ __launch_bounds__(256) void transpose_y(
    const u16* __restrict__ s0, u16* __restrict__ d0,
    const u16* __restrict__ s1, u16* __restrict__ d1,
    const u16* __restrict__ s2, u16* __restrict__ d2,
    const u16* __restrict__ s3, u16* __restrict__ d3)
{
    const int pz = blockIdx.z;
    const int b = pz >> 2, pl = pz & 3;
    const u16* src = pl == 0 ? s0 : pl == 1 ? s1 : pl == 2 ? s2 : s3;
    u16* dst = pl == 0 ? d0 : pl == 1 ? d1 : pl == 2 ? d2 : d3;
    const int o0 = blockIdx.x * 64, c0 = blockIdx.y * 64;
    __shared__ u16 t[64][72];
    const int tid = threadIdx.x;
#pragma unroll
    for (int rdx = tid; rdx < 512; rdx += 256) {
        const int c = rdx >> 3, oc = (rdx & 7) << 3;
        *(bh8*)&t[c][oc] = *(const bh8*)&src[((size_t)b * 512 + c0 + c) * 640 + o0 + oc];
    }
    __syncthreads();
#pragma unroll
    for (int wdx = tid; wdx < 512; wdx += 256) {
        const int o = wdx >> 3, cc = (wdx & 7) << 3;
        u16 v[8];
#pragma unroll
        for (int e = 0; e < 8; ++e) v[e] = t[cc + e][o];
        *(bh8*)&dst[((size_t)b * 640 + o0 + o) * 512 + c0 + cc] = *(bh8*)&v[0];
    }
}

// ---------------------------------------------------------------------------
// fp32 -> bf16 hi/lo planes
// ---------------------------------------------------------------------------
__global__ __launch_bounds__(256) void conv_split(
    const float* __restrict__ in, u16* __restrict__ hi, u16* __restrict__ lo, long n8)
{
    long i = (long)blockIdx.x * 256 + threadIdx.x;
    const long stride = (long)gridDim.x * 256;
    for (; i < n8; i += stride) {
        const float4 a = ((const float4*)in)[2 * i];
        const float4 b = ((const float4*)in)[2 * i + 1];
        const float v[8] = {a.x, a.y, a.z, a.w, b.x, b.y, b.z, b.w};
        unsigned hw[4], lw[4];
#pragma unroll
        for (int k = 0; k < 4; ++k) {
            const u16 h0 = f2bf(v[2 * k]), h1 = f2bf(v[2 * k + 1]);
            const u16 l0 = f2bf(v[2 * k] - bf2f(h0)), l1 = f2bf(v[2 * k + 1] - bf2f(h1));
            hw[k] = (unsigned)h0 | ((unsigned)h1 << 16);
            lw[k] = (unsigned)l0 | ((unsigned)l1 << 16);
        }
        *(uint4*)&hi[8 * i] = make_uint4(hw[0], hw[1], hw[2], hw[3]);
        *(uint4*)&lo[8 * i] = make_uint4(lw[0], lw[1], lw[2], lw[3]);
    }
}

// W [rows][2304] -> padded [640][2304] hi/lo, zero rows >= rows
__global__ __launch_bounds__(256) void conv_w_pad(
    const float* __restrict__ W, u16* __restrict__ hi, u16* __restrict__ lo,
    int rows, long n8)
{
    const long i = (long)blockIdx.x * 256 + threadIdx.x;
    if (i >= n8) return;
    const long e = i * 8;
    const int row = (int)(e / 2304);
    unsigned hw[4] = {0, 0, 0, 0}, lw[4] = {0, 0, 0, 0};
    if (row < rows) {
        const float4 a = ((const float4*)W)[2 * i];
        const float4 b = ((const float4*)W)[2 * i + 1];
        const float v[8] = {a.x, a.y, a.z, a.w, b.x, b.y, b.z, b.w};
#pragma unroll
        for (int k = 0; k < 4; ++k) {
            const u16 h0 = f2bf(v[2 * k]), h1 = f2bf(v[2 * k + 1]);
            const u16 l0 = f2bf(v[2 * k] - bf2f(h0)), l1 = f2bf(v[2 * k + 1] - bf2f(h1));
            hw[k] = (unsigned)h0 | ((unsigned)h1 << 16);
            lw[k] = (unsigned)l0 | ((unsigned)l1 << 16);
        }
    }
    *(uint4*)&hi[8 * i] = make_uint4(hw[0], hw[1], hw[2], hw[3]);
    *(uint4*)&lo[8 * i] = make_uint4(lw[0], lw[1], lw[2], lw[3]);
}

// ---------------------------------------------------------------------------
// row mean over o of ygx hi+lo planes [rows][640] -> out[row]
// ---------------------------------------------------------------------------
__global__ __launch_bounds__(256) void row_mean(
    const u16* __restrict__ Yh, const u16* __restrict__ Yl,
    float* __restrict__ out, int rows)
{
    const int l = threadIdx.x & 63;
    const int row = blockIdx.x * 4 + (threadIdx.x >> 6);
    if (row >= rows) return;
    const u16* ph = Yh + (size_t)row * 640;
    const u16* pl = Yl + (size_t)row * 640;
    float s = 0.f;
    struct U8 { u16 u[8]; };
    for (int k = l; k < 80; k += 64) {
        const U8 a = *(const U8*)&ph[k * 8];
        const U8 b = *(const U8*)&pl[k * 8];
#pragma unroll
        for (int e = 0; e < 8; ++e) s += bf2f(a.u[e]) + bf2f(b.u[e]);
    }
    for (int off = 32; off; off >>= 1) s += __shfl_down(s, off, 64);
    if (l == 0) out[row] = s * (1.f / 576.f);
}

// ---------------------------------------------------------------------------
// gate[b][d] = sigmoid(bn2(sum_o Wc2[o]*relu(bn1(sum_j Wc1[o][j]*yc[b][j][d]))))
// ---------------------------------------------------------------------------
__global__ __launch_bounds__(256)
void gate_kernel(const float* __restrict__ gxc, const float* __restrict__ GG,
                 const float* __restrict__ Wc1, const float* __restrict__ bn1,
                 const float* __restrict__ Wc2, const float* __restrict__ bn2,
                 float* __restrict__ gate, int IC, int D, int OC)
{
    const int b  = blockIdx.y;
    const int d0 = blockIdx.x * 64;

    __shared__ float yc_s[129][64];
    __shared__ float part[4][64];

    const int tid = threadIdx.x;
    for (int idx = tid; idx < 129 * 64; idx += 256) {
        const int j = idx >> 6, d = idx & 63;
        yc_s[j][d] = (j == 0) ? gxc[b * D + d0 + d]
                              : GG[((size_t)b * IC + (j - 1)) * D + d0 + d];
    }
    __syncthreads();

    const int d = tid & 63;
    const int q = tid >> 6;
    float acc2 = 0.f;
    for (int o = q * 16; o < q * 16 + 16; ++o) {
        float s = 0.f;
        const float* __restrict__ w = &Wc1[o * 129];
        for (int j = 0; j < 129; ++j) s = fmaf(w[j], yc_s[j][d], s);
        const float g1 = bn1[o], be1 = bn1[OC + o], m1 = bn1[2 * OC + o], v1 = bn1[3 * OC + o];
        const float sc = g1 / sqrtf(v1 + EPSV);
        const float w1 = fmaxf(s * sc + (be1 - m1 * sc), 0.f);
        acc2 = fmaf(Wc2[o], w1, acc2);
    }
    part[q][d] = acc2;
    __syncthreads();
    if (q == 0) {
        const float s = part[0][d] + part[1][d] + part[2][d] + part[3][d];
        const float g2 = bn2[0], be2 = bn2[1], m2 = bn2[2], v2 = bn2[3];
        const float sc = g2 / sqrtf(v2 + EPSV);
        const float wy = s * sc + (be2 - m2 * sc);
        gate[b * D + d0 + d] = 1.f / (1.f + expf(-wy));
    }
}

// ---------------------------------------------------------------------------
// out = x * (1 + gate[b][c])
// ---------------------------------------------------------------------------
__global__ __launch_bounds__(256)
void final_kernel(const float* __restrict__ x, const float* __restrict__ gate,
                  float* __restrict__ out, long n4, int sp4)
{
    long i = (long)blockIdx.x * blockDim.x + threadIdx.x;
    const long stride = (long)gridDim.x * blockDim.x;
    for (; i < n4; i += stride) {
        float4 v = ((const float4*)x)[i];
        const long bc = i / sp4;
        const float gm = 1.f + gate[bc];
        v.x *= gm; v.y *= gm; v.z *= gm; v.w *= gm;
        ((float4*)out)[i] = v;
    }
}

// ---------------------------------------------------------------------------
extern "C" void kernel_launch(void* const* d_in, const int* in_sizes, int n_in,
                              void* d_out, int out_size, void* d_ws, size_t ws_size,
                              hipStream_t stream)
{
    const float* x        = (const float*)d_in[0];
    const float* W_theta  = (const float*)d_in[1];
    const float* bn_theta = (const float*)d_in[2];
    const float* W_phi    = (const float*)d_in[3];
    const float* bn_phi   = (const float*)d_in[4];
    const float* W_gx     = (const float*)d_in[5];
    const float* bn_gx    = (const float*)d_in[6];
    const float* W_gg     = (const float*)d_in[7];
    const float* bn_gg    = (const float*)d_in[8];
    const float* W_c1     = (const float*)d_in[9];
    const float* bn_c1    = (const float*)d_in[10];
    const float* W_c2     = (const float*)d_in[11];
    const float* bn_c2    = (const float*)d_in[12];
    float* out = (float*)d_out;

    const int B = 32, C = 512, S = 2304, O = 576, OP = 640, IC = 128, OC = 64;
    const size_t P  = (size_t)B * C * OP;      // y-plane elems  (10,485,760)
    const size_t WP = (size_t)OP * S;          // W-plane elems  (1,474,560)
    const size_t UP = (size_t)B * IC * OP;     // U-plane elems  (2,621,440)

    // ---- d_out arena (dead before final_kernel) : 131.5 MB <= 151 MB ----
    u16* tth = (u16*)d_out;          // theta_t hi  [B*512][640]
    u16* ttl = tth + P;
    u16* pth = ttl + P;              // phi_t hi
    u16* ptl = pth + P;
    u16* Wgh = ptl + P;              // stage-1 W planes (gx, theta, phi)
    u16* Wgl = Wgh + WP;
    u16* Wth = Wgl + WP;
    u16* Wtl = Wth + WP;
    u16* Wph = Wtl + WP;
    u16* Wpl = Wph + WP;
    u16* wggh = Wpl + WP;            // Wgg planes [128][1024]
    u16* wggl = wggh + (size_t)IC * 1024;
    u16* u1h = wggl + (size_t)IC * 1024;
    u16* u1l = u1h + UP;
    u16* u2h = u1l + UP;
    u16* u2l = u2h + UP;
    float* GG = (float*)(u2l + UP);  // [B][128][512] fp32

    // ---- ws ----
    u16* Xhi  = (u16*)d_ws;                          // [B*512][2304]
    u16* Xlo  = Xhi + (size_t)B * C * S;
    u16* ygxh = Xlo + (size_t)B * C * S;             // [B*512][640]
    u16* ygxl = ygxh + P;
    float* gxc  = (float*)(ygxl + P);                // [B][512]
    float* gate = gxc + (size_t)B * C;               // [B][512]
    // transposed planes overlay the (dead after stage-1) X region:
    u16* tnth = (u16*)d_ws;                          // theta_nt [B*640][512]
    u16* tntl = tnth + P;
    u16* pnth = tntl + P;
    u16* pntl = pnth + P;

    const dim3 blk(256);

    // 1) weight conversions
    const long wN8 = (long)WP / 8;
    conv_w_pad<<<dim3((unsigned)(wN8 / 256)), blk, 0, stream>>>(W_gx,    Wgh, Wgl, O, wN8);
    conv_w_pad<<<dim3((unsigned)(wN8 / 256)), blk, 0, stream>>>(W_theta, Wth, Wtl, O, wN8);
    conv_w_pad<<<dim3((unsigned)(wN8 / 256)), blk, 0, stream>>>(W_phi,   Wph, Wpl, O, wN8);
    conv_split<<<dim3(64), blk, 0, stream>>>(W_gg, wggh, wggl, (long)IC * 1024 / 8);

    // 2) split X, stage-1 (3 weights fused), gx row-mean
    conv_split<<<dim3(2048), blk, 0, stream>>>(x, Xhi, Xlo, (long)B * C * S / 8);
    gemm_s1_v3<<<dim3(1920), blk, 0, stream>>>(
        Xhi, Xlo, Wgh, Wgl, Wth, Wtl, Wph, Wpl,
        bn_gx, bn_theta, bn_phi,
        ygxh, ygxl, tth, ttl, pth, ptl);
    row_mean<<<dim3(4096), blk, 0, stream>>>(ygxh, ygxl, gxc, B * C);

    // 3) transpose theta_t/phi_t hi+lo into ws (X region is dead now)
    transpose_y<<<dim3(10, 8, 128), blk, 0, stream>>>(
        tth, tnth, ttl, tntl, pth, pnth, ptl, pntl);

    // 4) U = Wgg * {phi_nt, theta_nt}
    gemm_u<<<dim3(320), blk, 0, stream>>>(wggh, wggl, tnth, tntl, pnth, pntl,
                                          u1h, u1l, u2h, u2l);

    // 5) GG = relu(bn(theta_t*U1^T + phi_t*U2^T))
    gemm_term<<<dim3(128), blk, 0, stream>>>(u1h, u1l, u2h, u2l,
                                             tth, ttl, pth, ptl, bn_gg, GG);

    // 6) gate
    gate_kernel<<<dim3(C / 64, B), blk, 0, stream>>>(gxc, GG, W_c1, bn_c1, W_c2, bn_c2,
                                                     gate, IC, C, OC);

    // 7) out = x * (1 + gate)
    final_kernel<<<dim3(2048), blk, 0, stream>>>(x, gate, out,
                                                 (long)B * C * S / 4, S / 4);
}